// Round 11
// baseline (671.329 us; speedup 1.0000x reference)
//
#include <hip/hip_runtime.h>

#define EPSBN 1e-5f
#define NB 512            // buckets (dst >> 9), 512 nodes per bucket
#define GB 512            // blocks for cnt/reorder tiles
#define SPLIT 8           // blocks per bucket in e_aggr

typedef float vf4 __attribute__((ext_vector_type(4)));
typedef int   vi2 __attribute__((ext_vector_type(2)));
typedef unsigned int uint32;

__device__ __forceinline__ float ftanh(float x) {
    return 1.0f - 2.0f / (__expf(2.0f * x) + 1.0f);
}

__device__ __forceinline__ float wave_sum(float v) {
#pragma unroll
    for (int off = 32; off > 0; off >>= 1) v += __shfl_down(v, off);
    return v;
}

__device__ __forceinline__ void z1_of(const float4 hi, const float4 hj,
                                      const float* __restrict__ w, const float* __restrict__ b,
                                      float* z) {
#pragma unroll
    for (int j = 0; j < 8; ++j) {
        z[j] = b[j]
             + hi.x * w[0 * 8 + j] + hi.y * w[1 * 8 + j] + hi.z * w[2 * 8 + j] + hi.w * w[3 * 8 + j]
             + hj.x * w[4 * 8 + j] + hj.y * w[5 * 8 + j] + hj.z * w[6 * 8 + j] + hj.w * w[7 * 8 + j];
    }
}

__device__ __forceinline__ void mat8x8(const float* u, const float* __restrict__ w,
                                       const float* __restrict__ b, float* z) {
#pragma unroll
    for (int j = 0; j < 8; ++j) {
        float t = b[j];
#pragma unroll
        for (int k = 0; k < 8; ++k) t += u[k] * w[k * 8 + j];
        z[j] = t;
    }
}

__device__ __forceinline__ void mat8x4(const float* u, const float* __restrict__ w,
                                       const float* __restrict__ b, float* z) {
#pragma unroll
    for (int c = 0; c < 4; ++c) {
        float t = b[c];
#pragma unroll
        for (int k = 0; k < 8; ++k) t += u[k] * w[k * 4 + c];
        z[c] = t;
    }
}

template <int NV>
__device__ __forceinline__ void block_reduce_atomics(float* a, float* __restrict__ sums) {
    __shared__ float red[NV * 4];
    int wid = threadIdx.x >> 6, lane = threadIdx.x & 63;
#pragma unroll
    for (int i = 0; i < NV; ++i) {
        float v = wave_sum(a[i]);
        if (lane == 0) red[i * 4 + wid] = v;
    }
    __syncthreads();
    if (threadIdx.x < NV) {
        float v = red[threadIdx.x * 4 + 0] + red[threadIdx.x * 4 + 1]
                + red[threadIdx.x * 4 + 2] + red[threadIdx.x * 4 + 3];
        atomicAdd(&sums[threadIdx.x], v);
    }
}

// compute BN scale/shift into LDS from raw sums (call with all threads; syncs inside)
__device__ __forceinline__ void fin_lds(const float* __restrict__ sums,
                                        const float* __restrict__ g, const float* __restrict__ be,
                                        int d, float inv, float* out) {
    int j = threadIdx.x;
    if (j < d) {
        float mu = sums[j] * inv;
        float var = sums[d + j] * inv - mu * mu;
        float s = g[j] * rsqrtf(var + EPSBN);
        out[j] = s;
        out[d + j] = be[j] - mu * s;
    }
    __syncthreads();
}

// ---------------- node input projection ----------------
__global__ __launch_bounds__(256) void k_h(const float* __restrict__ pos, const float* __restrict__ vel,
                                           const float* __restrict__ w, const float* __restrict__ b,
                                           float4* __restrict__ h, int n) {
    int i = blockIdx.x * blockDim.x + threadIdx.x;
    if (i >= n) return;
    float2 p = ((const float2*)pos)[i];
    float2 v = ((const float2*)vel)[i];
    float o[4];
#pragma unroll
    for (int d = 0; d < 4; ++d)
        o[d] = b[d] + p.x * w[0 * 4 + d] + p.y * w[1 * 4 + d] + v.x * w[2 * 4 + d] + v.y * w[3 * 4 + d];
    h[i] = make_float4(o[0], o[1], o[2], o[3]);
}

// ---------------- count: per-(block,bucket) histogram, LDS atomics only ----------------
__global__ __launch_bounds__(256) void k_cnt(const int* __restrict__ dst, uint32* __restrict__ cntmat,
                                             int E_, int T) {
    __shared__ uint32 hist[NB];
    for (int b = threadIdx.x; b < NB; b += 256) hist[b] = 0;
    __syncthreads();
    int lo = blockIdx.x * T, hi2 = min(E_, lo + T);
    for (int e = lo + threadIdx.x; e < hi2; e += 256) {
        int d = __builtin_nontemporal_load(dst + e);
        atomicAdd(&hist[d >> 9], 1u);
    }
    __syncthreads();
    for (int b = threadIdx.x; b < NB; b += 256)
        cntmat[(size_t)b * GB + blockIdx.x] = hist[b];
}

// block-scan of 512 uints (256 threads x 2), exclusive
__device__ __forceinline__ void scan512(uint32* v, uint32* excl_out, uint32* total) {
    __shared__ uint32 ts[256];
    uint32 local = v[0] + v[1];
    ts[threadIdx.x] = local;
    __syncthreads();
    for (int off = 1; off < 256; off <<= 1) {
        uint32 t = (threadIdx.x >= (uint32)off) ? ts[threadIdx.x - off] : 0u;
        __syncthreads();
        ts[threadIdx.x] += t;
        __syncthreads();
    }
    *excl_out = ts[threadIdx.x] - local;
    *total = ts[255];
}

__global__ __launch_bounds__(256) void k_scanA(uint32* __restrict__ cntmat, uint32* __restrict__ rowtot) {
    size_t base = (size_t)blockIdx.x * GB + threadIdx.x * 2;
    uint32 v[2];
    v[0] = cntmat[base]; v[1] = cntmat[base + 1];
    uint32 excl, tot;
    scan512(v, &excl, &tot);
    cntmat[base] = excl;
    cntmat[base + 1] = excl + v[0];
    if (threadIdx.x == 0) rowtot[blockIdx.x] = tot;
}

__global__ __launch_bounds__(256) void k_scanB(const uint32* __restrict__ rowtot, uint32* __restrict__ bbase) {
    uint32 v[2];
    v[0] = rowtot[threadIdx.x * 2]; v[1] = rowtot[threadIdx.x * 2 + 1];
    uint32 excl, tot;
    scan512(v, &excl, &tot);
    bbase[threadIdx.x * 2] = excl;
    bbase[threadIdx.x * 2 + 1] = excl + v[0];
    if (threadIdx.x == 0) bbase[NB] = tot;
}

// ---------------- reorder + fused z1 stats: 8B scatter + gather-compute ----------------
__global__ __launch_bounds__(256) void k_reorder(const int* __restrict__ idx, const float4* __restrict__ h,
                                                 const float* __restrict__ w1, const float* __restrict__ b1,
                                                 const uint32* __restrict__ cntmat, const uint32* __restrict__ bbase,
                                                 vi2* __restrict__ sp, float* __restrict__ sums, int E_, int T) {
    __shared__ uint32 cur[NB];
    for (int b = threadIdx.x; b < NB; b += 256)
        cur[b] = bbase[b] + cntmat[(size_t)b * GB + blockIdx.x];
    float a[16];
#pragma unroll
    for (int i = 0; i < 16; ++i) a[i] = 0.f;
    __syncthreads();
    int lo = blockIdx.x * T, hi2 = min(E_, lo + T);
    for (int e = lo + threadIdx.x; e < hi2; e += 256) {
        int s = __builtin_nontemporal_load(idx + e);
        int d = __builtin_nontemporal_load(idx + E_ + e);
        float4 hi = h[d], hj = h[s];
        float z[8];
        z1_of(hi, hj, w1, b1, z);
#pragma unroll
        for (int j = 0; j < 8; ++j) { a[j] += z[j]; a[8 + j] += z[j] * z[j]; }
        uint32 pos = atomicAdd(&cur[d >> 9], 1u);
        vi2 v = {s, d};
        sp[pos] = v;
    }
    block_reduce_atomics<16>(a, sums);
}

// ---------------- finalize BN stats -> scale/shift (fallback path only) ----------------
__global__ void k_fin(const float* __restrict__ sums, float* __restrict__ ss,
                      const float* __restrict__ g, const float* __restrict__ be,
                      int d, float inv_count) {
    int j = threadIdx.x;
    if (j >= d) return;
    float mu = sums[j] * inv_count;
    float var = sums[d + j] * inv_count - mu * mu;
    float s = g[j] * rsqrtf(var + EPSBN);
    ss[j] = s;
    ss[d + j] = be[j] - mu * s;
}

// ---------------- E2: grid-stride over sorted sp -> z2 stats (in-block fin) ----------------
__global__ __launch_bounds__(256) void e_pass2(const vi2* __restrict__ sp, const float4* __restrict__ h,
                                               const float* __restrict__ w1, const float* __restrict__ b1,
                                               const float* __restrict__ sums1,
                                               const float* __restrict__ g1, const float* __restrict__ be1,
                                               float invE,
                                               const float* __restrict__ w2, const float* __restrict__ b2,
                                               float* __restrict__ sums2, int E_) {
    __shared__ float ss1[16];
    fin_lds(sums1, g1, be1, 8, invE, ss1);
    float a[8];
#pragma unroll
    for (int i = 0; i < 8; ++i) a[i] = 0.f;
    int stride = gridDim.x * blockDim.x;
    for (int e = blockIdx.x * blockDim.x + threadIdx.x; e < E_; e += stride) {
        vi2 v = __builtin_nontemporal_load(&sp[e]);
        float4 hi = h[v.y], hj = h[v.x];
        float z[8], m1[8], z2[4];
        z1_of(hi, hj, w1, b1, z);
#pragma unroll
        for (int j = 0; j < 8; ++j) m1[j] = ftanh(z[j] * ss1[j] + ss1[8 + j]);
        mat8x4(m1, w2, b2, z2);
#pragma unroll
        for (int c = 0; c < 4; ++c) { a[c] += z2[c]; a[4 + c] += z2[c] * z2[c]; }
    }
    block_reduce_atomics<8>(a, sums2);
}

// ---------------- aggregate: SPLIT blocks per bucket; 2-edge unroll; LDS partials ----------------
__global__ __launch_bounds__(256) void e_aggr_part(const vi2* __restrict__ sp, const float4* __restrict__ h,
                                                   const uint32* __restrict__ bbase, const uint32* __restrict__ rowtot,
                                                   const float* __restrict__ w1, const float* __restrict__ b1,
                                                   const float* __restrict__ sums1,
                                                   const float* __restrict__ g1, const float* __restrict__ be1,
                                                   const float* __restrict__ sums2,
                                                   const float* __restrict__ g2, const float* __restrict__ be2,
                                                   float invE,
                                                   const float* __restrict__ w2, const float* __restrict__ b2,
                                                   float* __restrict__ part) {
    __shared__ float lacc[512 * 5];
    __shared__ float ss1[16];
    __shared__ float ss2[8];
    fin_lds(sums1, g1, be1, 8, invE, ss1);
    fin_lds(sums2, g2, be2, 4, invE, ss2);
    int bucket = blockIdx.x >> 3;          // / SPLIT
    int pi = blockIdx.x & (SPLIT - 1);
    int nodebase = bucket << 9;
    for (int k = threadIdx.x; k < 512 * 5; k += 256) lacc[k] = 0.f;
    __syncthreads();
    uint32 start = bbase[bucket];
    uint32 len = rowtot[bucket];
    uint32 chunk = (len + SPLIT - 1) / SPLIT;
    uint32 s0 = start + (uint32)pi * chunk;
    uint32 s1 = min(start + len, s0 + chunk);

    for (uint32 e = s0 + 2 * threadIdx.x; e < s1; e += 512) {
        // issue both sp loads, then all four h gathers, then compute
        vi2 v0 = __builtin_nontemporal_load(&sp[e]);
        bool has1 = (e + 1 < s1);
        vi2 v1 = has1 ? __builtin_nontemporal_load(&sp[e + 1]) : v0;
        float4 hi0 = h[v0.y], hj0 = h[v0.x];
        float4 hi1 = h[v1.y], hj1 = h[v1.x];
#pragma unroll
        for (int u = 0; u < 2; ++u) {
            if (u == 1 && !has1) break;
            float4 hi = (u == 0) ? hi0 : hi1;
            float4 hj = (u == 0) ? hj0 : hj1;
            int id = ((u == 0) ? v0.y : v1.y) - nodebase;
            bool zero = (hi.x == hj.x) && (hi.y == hj.y) && (hi.z == hj.z) && (hi.w == hj.w);
            if (!zero) {
                float z[8], m1[8], z2[4], m2[4];
                z1_of(hi, hj, w1, b1, z);
#pragma unroll
                for (int j = 0; j < 8; ++j) m1[j] = ftanh(z[j] * ss1[j] + ss1[8 + j]);
                mat8x4(m1, w2, b2, z2);
#pragma unroll
                for (int c = 0; c < 4; ++c) m2[c] = ftanh(z2[c] * ss2[c] + ss2[4 + c]);
#pragma unroll
                for (int c = 0; c < 4; ++c) atomicAdd(&lacc[id * 5 + c], m2[c]);
            }
            atomicAdd(&lacc[id * 5 + 4], 1.0f);
        }
    }
    __syncthreads();
    float* pp = part + (size_t)blockIdx.x * (512 * 5);
    for (int k = threadIdx.x; k < 512 * 5; k += 256)
        __builtin_nontemporal_store(lacc[k], pp + k);
}

// ---------------- merge SPLIT partials per node -> acc record ----------------
__global__ __launch_bounds__(256) void k_merge(const float* __restrict__ part, float* __restrict__ acc, int n) {
    int node = blockIdx.x * 256 + threadIdx.x;
    if (node >= n) return;
    int bucket = node >> 9, id = node & 511;
    float v0 = 0.f, v1 = 0.f, v2 = 0.f, v3 = 0.f, v4 = 0.f;
#pragma unroll
    for (int p = 0; p < SPLIT; ++p) {
        const float* pp = part + (size_t)(bucket * SPLIT + p) * (512 * 5) + id * 5;
        v0 += pp[0]; v1 += pp[1]; v2 += pp[2]; v3 += pp[3]; v4 += pp[4];
    }
    float* ap = acc + 8 * (size_t)node;
    ap[0] = v0; ap[1] = v1; ap[2] = v2; ap[3] = v3; ap[4] = v4;
}

// ---------------- fallback edge kernels (round-1 style, used if ws too small) ----------------
__global__ __launch_bounds__(256) void fb_stats1(const int* __restrict__ idx, const float4* __restrict__ h,
                                                 const float* __restrict__ w1, const float* __restrict__ b1,
                                                 float* __restrict__ sums, float* __restrict__ acc, int E_) {
    float a[16];
#pragma unroll
    for (int i = 0; i < 16; ++i) a[i] = 0.f;
    int stride = gridDim.x * blockDim.x;
    for (int e = blockIdx.x * blockDim.x + threadIdx.x; e < E_; e += stride) {
        int s = __builtin_nontemporal_load(idx + e);
        int d = __builtin_nontemporal_load(idx + E_ + e);
        float4 hi = h[d], hj = h[s];
        float z[8];
        z1_of(hi, hj, w1, b1, z);
#pragma unroll
        for (int j = 0; j < 8; ++j) { a[j] += z[j]; a[8 + j] += z[j] * z[j]; }
        atomicAdd(acc + 8 * (size_t)d + 4, 1.0f);
    }
    block_reduce_atomics<16>(a, sums);
}

__global__ __launch_bounds__(256) void fb_stats2(const int* __restrict__ idx, const float4* __restrict__ h,
                                                 const float* __restrict__ w1, const float* __restrict__ b1,
                                                 const float* __restrict__ ss1,
                                                 const float* __restrict__ w2, const float* __restrict__ b2,
                                                 float* __restrict__ sums2, int E_) {
    float a[8];
#pragma unroll
    for (int i = 0; i < 8; ++i) a[i] = 0.f;
    int stride = gridDim.x * blockDim.x;
    for (int e = blockIdx.x * blockDim.x + threadIdx.x; e < E_; e += stride) {
        int s = __builtin_nontemporal_load(idx + e);
        int d = __builtin_nontemporal_load(idx + E_ + e);
        float4 hi = h[d], hj = h[s];
        float z[8], m1[8], z2[4];
        z1_of(hi, hj, w1, b1, z);
#pragma unroll
        for (int j = 0; j < 8; ++j) m1[j] = ftanh(z[j] * ss1[j] + ss1[8 + j]);
        mat8x4(m1, w2, b2, z2);
#pragma unroll
        for (int c = 0; c < 4; ++c) { a[c] += z2[c]; a[4 + c] += z2[c] * z2[c]; }
    }
    block_reduce_atomics<8>(a, sums2);
}

__global__ __launch_bounds__(256) void fb_scatter(const int* __restrict__ idx, const float4* __restrict__ h,
                                                  const float* __restrict__ w1, const float* __restrict__ b1,
                                                  const float* __restrict__ ss1,
                                                  const float* __restrict__ w2, const float* __restrict__ b2,
                                                  const float* __restrict__ ss2,
                                                  float* __restrict__ acc, int E_) {
    int stride = gridDim.x * blockDim.x;
    for (int e = blockIdx.x * blockDim.x + threadIdx.x; e < E_; e += stride) {
        int s = __builtin_nontemporal_load(idx + e);
        int d = __builtin_nontemporal_load(idx + E_ + e);
        float4 hi = h[d], hj = h[s];
        bool zero = (hi.x == hj.x) && (hi.y == hj.y) && (hi.z == hj.z) && (hi.w == hj.w);
        if (zero) continue;
        float z[8], m1[8], z2[4], m2[4];
        z1_of(hi, hj, w1, b1, z);
#pragma unroll
        for (int j = 0; j < 8; ++j) m1[j] = ftanh(z[j] * ss1[j] + ss1[8 + j]);
        mat8x4(m1, w2, b2, z2);
#pragma unroll
        for (int c = 0; c < 4; ++c) m2[c] = ftanh(z2[c] * ss2[c] + ss2[4 + c]);
        float* ap = acc + 8 * (size_t)d;
        atomicAdd(ap + 0, m2[0]);
        atomicAdd(ap + 1, m2[1]);
        atomicAdd(ap + 2, m2[2]);
        atomicAdd(ap + 3, m2[3]);
    }
}

// ---------------- node update MLP ----------------
__device__ __forceinline__ void load_u(int i, const float4* __restrict__ h,
                                       const float* __restrict__ acc, float* u) {
    float4 hv = h[i];
    const float* ap = acc + 8 * (size_t)i;
    float c = fmaxf(ap[4], 1.0f);
    u[0] = hv.x; u[1] = hv.y; u[2] = hv.z; u[3] = hv.w;
    u[4] = ap[0]; u[5] = ap[1]; u[6] = ap[2] / c; u[7] = ap[3] / c;
}

__global__ __launch_bounds__(256) void n_stats1(const float4* __restrict__ h,
                                                const float* __restrict__ acc,
                                                const float* __restrict__ w, const float* __restrict__ b,
                                                float* __restrict__ sums, int n) {
    float a[16];
#pragma unroll
    for (int i = 0; i < 16; ++i) a[i] = 0.f;
    int stride = gridDim.x * blockDim.x;
    for (int i = blockIdx.x * blockDim.x + threadIdx.x; i < n; i += stride) {
        float u[8], z[8];
        load_u(i, h, acc, u);
        mat8x8(u, w, b, z);
#pragma unroll
        for (int j = 0; j < 8; ++j) { a[j] += z[j]; a[8 + j] += z[j] * z[j]; }
    }
    block_reduce_atomics<16>(a, sums);
}

__global__ __launch_bounds__(256) void n_stats2(const float4* __restrict__ h,
                                                const float* __restrict__ acc,
                                                const float* __restrict__ w1, const float* __restrict__ b1,
                                                const float* __restrict__ sums3,
                                                const float* __restrict__ g3, const float* __restrict__ be3,
                                                float invN,
                                                const float* __restrict__ w2, const float* __restrict__ b2,
                                                float* __restrict__ sums, int n) {
    __shared__ float ss3[16];
    fin_lds(sums3, g3, be3, 8, invN, ss3);
    float a[8];
#pragma unroll
    for (int i = 0; i < 8; ++i) a[i] = 0.f;
    int stride = gridDim.x * blockDim.x;
    for (int i = blockIdx.x * blockDim.x + threadIdx.x; i < n; i += stride) {
        float u[8], z[8], u1[8], z4[4];
        load_u(i, h, acc, u);
        mat8x8(u, w1, b1, z);
#pragma unroll
        for (int j = 0; j < 8; ++j) u1[j] = ftanh(z[j] * ss3[j] + ss3[8 + j]);
        mat8x4(u1, w2, b2, z4);
#pragma unroll
        for (int c = 0; c < 4; ++c) { a[c] += z4[c]; a[4 + c] += z4[c] * z4[c]; }
    }
    block_reduce_atomics<8>(a, sums);
}

__global__ __launch_bounds__(256) void n_final(const float4* __restrict__ h,
                                               const float* __restrict__ acc,
                                               const float* __restrict__ w1, const float* __restrict__ b1,
                                               const float* __restrict__ sums3,
                                               const float* __restrict__ g3, const float* __restrict__ be3,
                                               const float* __restrict__ sums4,
                                               const float* __restrict__ g4, const float* __restrict__ be4,
                                               float invN,
                                               const float* __restrict__ w2, const float* __restrict__ b2,
                                               const float* __restrict__ pw, const float* __restrict__ pb,
                                               float2* __restrict__ out, int n) {
    __shared__ float ss3[16];
    __shared__ float ss4[8];
    fin_lds(sums3, g3, be3, 8, invN, ss3);
    fin_lds(sums4, g4, be4, 4, invN, ss4);
    int stride = gridDim.x * blockDim.x;
    for (int i = blockIdx.x * blockDim.x + threadIdx.x; i < n; i += stride) {
        float u[8], z[8], u1[8], z4[4], u2[4];
        load_u(i, h, acc, u);
        mat8x8(u, w1, b1, z);
#pragma unroll
        for (int j = 0; j < 8; ++j) u1[j] = ftanh(z[j] * ss3[j] + ss3[8 + j]);
        mat8x4(u1, w2, b2, z4);
#pragma unroll
        for (int c = 0; c < 4; ++c) u2[c] = ftanh(z4[c] * ss4[c] + ss4[4 + c]);
        float o0 = pb[0] + u2[0] * pw[0] + u2[1] * pw[2] + u2[2] * pw[4] + u2[3] * pw[6];
        float o1 = pb[1] + u2[0] * pw[1] + u2[1] * pw[3] + u2[2] * pw[5] + u2[3] * pw[7];
        out[i] = make_float2(o0, o1);
    }
}

extern "C" void kernel_launch(void* const* d_in, const int* in_sizes, int n_in,
                              void* d_out, int out_size, void* d_ws, size_t ws_size,
                              hipStream_t stream) {
    const float* pos  = (const float*)d_in[0];
    const float* vel  = (const float*)d_in[1];
    const int*   eidx = (const int*)d_in[2];
    const float* lin_w = (const float*)d_in[3];
    const float* lin_b = (const float*)d_in[4];
    const float* mw1 = (const float*)d_in[5];
    const float* mb1 = (const float*)d_in[6];
    const float* mg1 = (const float*)d_in[7];
    const float* mbe1 = (const float*)d_in[8];
    const float* mw2 = (const float*)d_in[9];
    const float* mb2 = (const float*)d_in[10];
    const float* mg2 = (const float*)d_in[11];
    const float* mbe2 = (const float*)d_in[12];
    const float* uw1 = (const float*)d_in[13];
    const float* ub1 = (const float*)d_in[14];
    const float* ug1 = (const float*)d_in[15];
    const float* ube1 = (const float*)d_in[16];
    const float* uw2 = (const float*)d_in[17];
    const float* ub2 = (const float*)d_in[18];
    const float* ug2 = (const float*)d_in[19];
    const float* ube2 = (const float*)d_in[20];
    const float* pw = (const float*)d_in[21];
    const float* pb = (const float*)d_in[22];

    int n  = in_sizes[0] / 2;
    int E_ = in_sizes[2] / 2;
    float invE = 1.0f / (float)E_;
    float invN = 1.0f / (float)n;

    // ---- workspace layout (bump allocator, 16B aligned) ----
    char* base = (char*)d_ws;
    size_t off = 0;
    auto alloc = [&](size_t bytes) {
        off = (off + 15) & ~(size_t)15;
        void* p = base + off;
        off += bytes;
        return p;
    };
    int nbuckets = (n + 511) >> 9;
    float4* h      = (float4*)alloc(16 * (size_t)n);                 // 4 MB
    float*  acc    = (float*)alloc(32 * (size_t)n);                  // 8 MB
    float*  sums   = (float*)alloc(512);
    float*  ss     = sums + 64;
    uint32* bbase  = (uint32*)alloc(4 * (NB + 1));
    uint32* rowtot = (uint32*)alloc(4 * NB);
    uint32* cntmat = (uint32*)alloc(4 * (size_t)NB * GB);            // 1 MB
    float*  part   = (float*)alloc(4 * (size_t)nbuckets * SPLIT * 512 * 5); // ~40 MB
    vi2*    sp     = (vi2*)alloc(8 * (size_t)E_);                    // 64 MB
    size_t need_sort = off;                                           // ~118 MB

    bool big = ws_size >= need_sort;

    int nblk = (n + 255) / 256;
    int T = (E_ + GB - 1) / GB;

    k_h<<<nblk, 256, 0, stream>>>(pos, vel, lin_w, lin_b, h, n);

    if (big) {
        (void)hipMemsetAsync(sums, 0, 256, stream);   // zero the 64 accumulator floats

        k_cnt<<<GB, 256, 0, stream>>>(eidx + E_, cntmat, E_, T);
        k_scanA<<<NB, 256, 0, stream>>>(cntmat, rowtot);
        k_scanB<<<1, 256, 0, stream>>>(rowtot, bbase);

        k_reorder<<<GB, 256, 0, stream>>>(eidx, h, mw1, mb1, cntmat, bbase, sp, sums, E_, T);

        e_pass2<<<2048, 256, 0, stream>>>(sp, h, mw1, mb1, sums, mg1, mbe1, invE,
                                          mw2, mb2, sums + 16, E_);

        e_aggr_part<<<nbuckets * SPLIT, 256, 0, stream>>>(sp, h, bbase, rowtot,
                                                          mw1, mb1, sums, mg1, mbe1,
                                                          sums + 16, mg2, mbe2, invE,
                                                          mw2, mb2, part);
        k_merge<<<nblk, 256, 0, stream>>>(part, acc, n);

        n_stats1<<<nblk, 256, 0, stream>>>(h, acc, uw1, ub1, sums + 24, n);
        n_stats2<<<nblk, 256, 0, stream>>>(h, acc, uw1, ub1, sums + 24, ug1, ube1, invN,
                                           uw2, ub2, sums + 40, n);
        n_final<<<nblk, 256, 0, stream>>>(h, acc, uw1, ub1, sums + 24, ug1, ube1,
                                          sums + 40, ug2, ube2, invN,
                                          uw2, ub2, pw, pb, (float2*)d_out, n);
    } else {
        (void)hipMemsetAsync(acc, 0, 32 * (size_t)n + 256, stream);

        fb_stats1<<<4096, 256, 0, stream>>>(eidx, h, mw1, mb1, sums, acc, E_);
        k_fin<<<1, 64, 0, stream>>>(sums, ss, mg1, mbe1, 8, invE);

        fb_stats2<<<4096, 256, 0, stream>>>(eidx, h, mw1, mb1, ss, mw2, mb2, sums + 16, E_);
        k_fin<<<1, 64, 0, stream>>>(sums + 16, ss + 16, mg2, mbe2, 4, invE);

        fb_scatter<<<4096, 256, 0, stream>>>(eidx, h, mw1, mb1, ss, mw2, mb2, ss + 16, acc, E_);

        n_stats1<<<nblk, 256, 0, stream>>>(h, acc, uw1, ub1, sums + 24, n);
        n_stats2<<<nblk, 256, 0, stream>>>(h, acc, uw1, ub1, sums + 24, ug1, ube1, invN,
                                           uw2, ub2, sums + 40, n);
        n_final<<<nblk, 256, 0, stream>>>(h, acc, uw1, ub1, sums + 24, ug1, ube1,
                                          sums + 40, ug2, ube2, invN,
                                          uw2, ub2, pw, pb, (float2*)d_out, n);
    }
}

// Round 12
// 664.231 us; speedup vs baseline: 1.0107x; 1.0107x over previous
//
#include <hip/hip_runtime.h>

#define EPSBN 1e-5f
#define NB 512            // buckets (dst >> 9), 512 nodes per bucket
#define GB 512            // blocks for cnt/reorder tiles
#define SPLIT 8           // blocks per bucket in e_aggr

typedef float vf4 __attribute__((ext_vector_type(4)));
typedef int   vi2 __attribute__((ext_vector_type(2)));
typedef int   vi4 __attribute__((ext_vector_type(4)));
typedef unsigned int uint32;

__device__ __forceinline__ float ftanh(float x) {
    return 1.0f - 2.0f / (__expf(2.0f * x) + 1.0f);
}

__device__ __forceinline__ float wave_sum(float v) {
#pragma unroll
    for (int off = 32; off > 0; off >>= 1) v += __shfl_down(v, off);
    return v;
}

__device__ __forceinline__ void z1_of(const float4 hi, const float4 hj,
                                      const float* __restrict__ w, const float* __restrict__ b,
                                      float* z) {
#pragma unroll
    for (int j = 0; j < 8; ++j) {
        z[j] = b[j]
             + hi.x * w[0 * 8 + j] + hi.y * w[1 * 8 + j] + hi.z * w[2 * 8 + j] + hi.w * w[3 * 8 + j]
             + hj.x * w[4 * 8 + j] + hj.y * w[5 * 8 + j] + hj.z * w[6 * 8 + j] + hj.w * w[7 * 8 + j];
    }
}

__device__ __forceinline__ void mat8x8(const float* u, const float* __restrict__ w,
                                       const float* __restrict__ b, float* z) {
#pragma unroll
    for (int j = 0; j < 8; ++j) {
        float t = b[j];
#pragma unroll
        for (int k = 0; k < 8; ++k) t += u[k] * w[k * 8 + j];
        z[j] = t;
    }
}

__device__ __forceinline__ void mat8x4(const float* u, const float* __restrict__ w,
                                       const float* __restrict__ b, float* z) {
#pragma unroll
    for (int c = 0; c < 4; ++c) {
        float t = b[c];
#pragma unroll
        for (int k = 0; k < 8; ++k) t += u[k] * w[k * 4 + c];
        z[c] = t;
    }
}

template <int NV>
__device__ __forceinline__ void block_reduce_atomics(float* a, float* __restrict__ sums) {
    __shared__ float red[NV * 4];
    int wid = threadIdx.x >> 6, lane = threadIdx.x & 63;
#pragma unroll
    for (int i = 0; i < NV; ++i) {
        float v = wave_sum(a[i]);
        if (lane == 0) red[i * 4 + wid] = v;
    }
    __syncthreads();
    if (threadIdx.x < NV) {
        float v = red[threadIdx.x * 4 + 0] + red[threadIdx.x * 4 + 1]
                + red[threadIdx.x * 4 + 2] + red[threadIdx.x * 4 + 3];
        atomicAdd(&sums[threadIdx.x], v);
    }
}

// compute BN scale/shift into LDS from raw sums (call with all threads; syncs inside)
__device__ __forceinline__ void fin_lds(const float* __restrict__ sums,
                                        const float* __restrict__ g, const float* __restrict__ be,
                                        int d, float inv, float* out) {
    int j = threadIdx.x;
    if (j < d) {
        float mu = sums[j] * inv;
        float var = sums[d + j] * inv - mu * mu;
        float s = g[j] * rsqrtf(var + EPSBN);
        out[j] = s;
        out[d + j] = be[j] - mu * s;
    }
    __syncthreads();
}

// ---------------- node input projection ----------------
__global__ __launch_bounds__(256) void k_h(const float* __restrict__ pos, const float* __restrict__ vel,
                                           const float* __restrict__ w, const float* __restrict__ b,
                                           float4* __restrict__ h, int n) {
    int i = blockIdx.x * blockDim.x + threadIdx.x;
    if (i >= n) return;
    float2 p = ((const float2*)pos)[i];
    float2 v = ((const float2*)vel)[i];
    float o[4];
#pragma unroll
    for (int d = 0; d < 4; ++d)
        o[d] = b[d] + p.x * w[0 * 4 + d] + p.y * w[1 * 4 + d] + v.x * w[2 * 4 + d] + v.y * w[3 * 4 + d];
    h[i] = make_float4(o[0], o[1], o[2], o[3]);
}

// ---------------- count: per-(block,bucket) histogram, 4 NT loads per iter ----------------
__global__ __launch_bounds__(256) void k_cnt(const int* __restrict__ dst, uint32* __restrict__ cntmat,
                                             int E_, int T) {
    __shared__ uint32 hist[NB];
    for (int b = threadIdx.x; b < NB; b += 256) hist[b] = 0;
    __syncthreads();
    int lo = blockIdx.x * T, hi2 = min(E_, lo + T);
    for (int e0 = lo + 4 * threadIdx.x; e0 < hi2; e0 += 1024) {
        int m = min(4, hi2 - e0);
        if (m == 4) {
            int d0 = __builtin_nontemporal_load(dst + e0);
            int d1 = __builtin_nontemporal_load(dst + e0 + 1);
            int d2 = __builtin_nontemporal_load(dst + e0 + 2);
            int d3 = __builtin_nontemporal_load(dst + e0 + 3);
            atomicAdd(&hist[d0 >> 9], 1u);
            atomicAdd(&hist[d1 >> 9], 1u);
            atomicAdd(&hist[d2 >> 9], 1u);
            atomicAdd(&hist[d3 >> 9], 1u);
        } else {
            for (int k = 0; k < m; ++k) {
                int d = __builtin_nontemporal_load(dst + e0 + k);
                atomicAdd(&hist[d >> 9], 1u);
            }
        }
    }
    __syncthreads();
    for (int b = threadIdx.x; b < NB; b += 256)
        cntmat[(size_t)b * GB + blockIdx.x] = hist[b];
}

// block-scan of 512 uints (256 threads x 2), exclusive
__device__ __forceinline__ void scan512(uint32* v, uint32* excl_out, uint32* total) {
    __shared__ uint32 ts[256];
    uint32 local = v[0] + v[1];
    ts[threadIdx.x] = local;
    __syncthreads();
    for (int off = 1; off < 256; off <<= 1) {
        uint32 t = (threadIdx.x >= (uint32)off) ? ts[threadIdx.x - off] : 0u;
        __syncthreads();
        ts[threadIdx.x] += t;
        __syncthreads();
    }
    *excl_out = ts[threadIdx.x] - local;
    *total = ts[255];
}

__global__ __launch_bounds__(256) void k_scanA(uint32* __restrict__ cntmat, uint32* __restrict__ rowtot) {
    size_t base = (size_t)blockIdx.x * GB + threadIdx.x * 2;
    uint32 v[2];
    v[0] = cntmat[base]; v[1] = cntmat[base + 1];
    uint32 excl, tot;
    scan512(v, &excl, &tot);
    cntmat[base] = excl;
    cntmat[base + 1] = excl + v[0];
    if (threadIdx.x == 0) rowtot[blockIdx.x] = tot;
}

__global__ __launch_bounds__(256) void k_scanB(const uint32* __restrict__ rowtot, uint32* __restrict__ bbase) {
    uint32 v[2];
    v[0] = rowtot[threadIdx.x * 2]; v[1] = rowtot[threadIdx.x * 2 + 1];
    uint32 excl, tot;
    scan512(v, &excl, &tot);
    bbase[threadIdx.x * 2] = excl;
    bbase[threadIdx.x * 2 + 1] = excl + v[0];
    if (threadIdx.x == 0) bbase[NB] = tot;
}

// ---------------- reorder: pure 8B scatter, 4-edge batches (no h, no stats) ----------------
__global__ __launch_bounds__(256) void k_reorder(const int* __restrict__ idx,
                                                 const uint32* __restrict__ cntmat, const uint32* __restrict__ bbase,
                                                 vi2* __restrict__ sp, int E_, int T) {
    __shared__ uint32 cur[NB];
    for (int b = threadIdx.x; b < NB; b += 256)
        cur[b] = bbase[b] + cntmat[(size_t)b * GB + blockIdx.x];
    __syncthreads();
    int lo = blockIdx.x * T, hi2 = min(E_, lo + T);
    for (int e0 = lo + 4 * threadIdx.x; e0 < hi2; e0 += 1024) {
        int m = min(4, hi2 - e0);
        if (m == 4) {
            int s0 = __builtin_nontemporal_load(idx + e0);
            int s1 = __builtin_nontemporal_load(idx + e0 + 1);
            int s2 = __builtin_nontemporal_load(idx + e0 + 2);
            int s3 = __builtin_nontemporal_load(idx + e0 + 3);
            int d0 = __builtin_nontemporal_load(idx + E_ + e0);
            int d1 = __builtin_nontemporal_load(idx + E_ + e0 + 1);
            int d2 = __builtin_nontemporal_load(idx + E_ + e0 + 2);
            int d3 = __builtin_nontemporal_load(idx + E_ + e0 + 3);
            uint32 p0 = atomicAdd(&cur[d0 >> 9], 1u);
            uint32 p1 = atomicAdd(&cur[d1 >> 9], 1u);
            uint32 p2 = atomicAdd(&cur[d2 >> 9], 1u);
            uint32 p3 = atomicAdd(&cur[d3 >> 9], 1u);
            vi2 v0 = {s0, d0}; sp[p0] = v0;
            vi2 v1 = {s1, d1}; sp[p1] = v1;
            vi2 v2 = {s2, d2}; sp[p2] = v2;
            vi2 v3 = {s3, d3}; sp[p3] = v3;
        } else {
            for (int k = 0; k < m; ++k) {
                int s = __builtin_nontemporal_load(idx + e0 + k);
                int d = __builtin_nontemporal_load(idx + E_ + e0 + k);
                uint32 pos = atomicAdd(&cur[d >> 9], 1u);
                vi2 v = {s, d};
                sp[pos] = v;
            }
        }
    }
}

// ---------------- finalize BN stats -> scale/shift (fallback path only) ----------------
__global__ void k_fin(const float* __restrict__ sums, float* __restrict__ ss,
                      const float* __restrict__ g, const float* __restrict__ be,
                      int d, float inv_count) {
    int j = threadIdx.x;
    if (j >= d) return;
    float mu = sums[j] * inv_count;
    float var = sums[d + j] * inv_count - mu * mu;
    float s = g[j] * rsqrtf(var + EPSBN);
    ss[j] = s;
    ss[d + j] = be[j] - mu * s;
}

// ---------------- E-stats1: 4-edge batches over sorted sp ----------------
__global__ __launch_bounds__(256) void e_stats1(const vi2* __restrict__ sp, const float4* __restrict__ h,
                                                const float* __restrict__ w1, const float* __restrict__ b1,
                                                float* __restrict__ sums, int E_) {
    float a[16];
#pragma unroll
    for (int i = 0; i < 16; ++i) a[i] = 0.f;
    int stride4 = gridDim.x * blockDim.x * 4;
    for (int e0 = (blockIdx.x * blockDim.x + threadIdx.x) * 4; e0 < E_; e0 += stride4) {
        int m = min(4, E_ - e0);
        if (m == 4) {
            vi4 A = __builtin_nontemporal_load((const vi4*)(sp + e0));
            vi4 B = __builtin_nontemporal_load((const vi4*)(sp + e0 + 2));
            float4 hi0 = h[A.y], hj0 = h[A.x];
            float4 hi1 = h[A.w], hj1 = h[A.z];
            float4 hi2 = h[B.y], hj2 = h[B.x];
            float4 hi3 = h[B.w], hj3 = h[B.z];
            float z[8];
            z1_of(hi0, hj0, w1, b1, z);
#pragma unroll
            for (int j = 0; j < 8; ++j) { a[j] += z[j]; a[8 + j] += z[j] * z[j]; }
            z1_of(hi1, hj1, w1, b1, z);
#pragma unroll
            for (int j = 0; j < 8; ++j) { a[j] += z[j]; a[8 + j] += z[j] * z[j]; }
            z1_of(hi2, hj2, w1, b1, z);
#pragma unroll
            for (int j = 0; j < 8; ++j) { a[j] += z[j]; a[8 + j] += z[j] * z[j]; }
            z1_of(hi3, hj3, w1, b1, z);
#pragma unroll
            for (int j = 0; j < 8; ++j) { a[j] += z[j]; a[8 + j] += z[j] * z[j]; }
        } else {
            for (int k = 0; k < m; ++k) {
                vi2 v = __builtin_nontemporal_load(&sp[e0 + k]);
                float4 hi = h[v.y], hj = h[v.x];
                float z[8];
                z1_of(hi, hj, w1, b1, z);
#pragma unroll
                for (int j = 0; j < 8; ++j) { a[j] += z[j]; a[8 + j] += z[j] * z[j]; }
            }
        }
    }
    block_reduce_atomics<16>(a, sums);
}

// ---------------- E2: 4-edge batches -> z2 stats (in-block fin) ----------------
__global__ __launch_bounds__(256) void e_pass2(const vi2* __restrict__ sp, const float4* __restrict__ h,
                                               const float* __restrict__ w1, const float* __restrict__ b1,
                                               const float* __restrict__ sums1,
                                               const float* __restrict__ g1, const float* __restrict__ be1,
                                               float invE,
                                               const float* __restrict__ w2, const float* __restrict__ b2,
                                               float* __restrict__ sums2, int E_) {
    __shared__ float ss1[16];
    fin_lds(sums1, g1, be1, 8, invE, ss1);
    float a[8];
#pragma unroll
    for (int i = 0; i < 8; ++i) a[i] = 0.f;
    int stride4 = gridDim.x * blockDim.x * 4;
    for (int e0 = (blockIdx.x * blockDim.x + threadIdx.x) * 4; e0 < E_; e0 += stride4) {
        int m = min(4, E_ - e0);
        float4 hi[4], hj[4];
        int cnt;
        if (m == 4) {
            vi4 A = __builtin_nontemporal_load((const vi4*)(sp + e0));
            vi4 B = __builtin_nontemporal_load((const vi4*)(sp + e0 + 2));
            hi[0] = h[A.y]; hj[0] = h[A.x];
            hi[1] = h[A.w]; hj[1] = h[A.z];
            hi[2] = h[B.y]; hj[2] = h[B.x];
            hi[3] = h[B.w]; hj[3] = h[B.z];
            cnt = 4;
        } else {
            for (int k = 0; k < m; ++k) {
                vi2 v = __builtin_nontemporal_load(&sp[e0 + k]);
                hi[k] = h[v.y]; hj[k] = h[v.x];
            }
            cnt = m;
        }
        for (int k = 0; k < cnt; ++k) {
            float z[8], m1[8], z2[4];
            z1_of(hi[k], hj[k], w1, b1, z);
#pragma unroll
            for (int j = 0; j < 8; ++j) m1[j] = ftanh(z[j] * ss1[j] + ss1[8 + j]);
            mat8x4(m1, w2, b2, z2);
#pragma unroll
            for (int c = 0; c < 4; ++c) { a[c] += z2[c]; a[4 + c] += z2[c] * z2[c]; }
        }
    }
    block_reduce_atomics<8>(a, sums2);
}

// ---------------- aggregate: SPLIT blocks per bucket; 4-edge pipeline; LDS partials ----------------
__global__ __launch_bounds__(256) void e_aggr_part(const vi2* __restrict__ sp, const float4* __restrict__ h,
                                                   const uint32* __restrict__ bbase, const uint32* __restrict__ rowtot,
                                                   const float* __restrict__ w1, const float* __restrict__ b1,
                                                   const float* __restrict__ sums1,
                                                   const float* __restrict__ g1, const float* __restrict__ be1,
                                                   const float* __restrict__ sums2,
                                                   const float* __restrict__ g2, const float* __restrict__ be2,
                                                   float invE,
                                                   const float* __restrict__ w2, const float* __restrict__ b2,
                                                   float* __restrict__ part) {
    __shared__ float lacc[512 * 5];
    __shared__ float ss1[16];
    __shared__ float ss2[8];
    fin_lds(sums1, g1, be1, 8, invE, ss1);
    fin_lds(sums2, g2, be2, 4, invE, ss2);
    int bucket = blockIdx.x >> 3;          // / SPLIT
    int pi = blockIdx.x & (SPLIT - 1);
    int nodebase = bucket << 9;
    for (int k = threadIdx.x; k < 512 * 5; k += 256) lacc[k] = 0.f;
    __syncthreads();
    uint32 start = bbase[bucket];
    uint32 len = rowtot[bucket];
    uint32 chunk = (len + SPLIT - 1) / SPLIT;
    uint32 s0 = start + (uint32)pi * chunk;
    uint32 s1 = min(start + len, s0 + chunk);

    for (uint32 e0 = s0 + 4 * threadIdx.x; e0 < s1; e0 += 1024) {
        int m = (int)min(4u, s1 - e0);
        vi2 v[4];
        float4 hi[4], hj[4];
        // issue all sp loads, then all gathers
        for (int k = 0; k < m; ++k) v[k] = __builtin_nontemporal_load(&sp[e0 + k]);
        for (int k = 0; k < m; ++k) { hi[k] = h[v[k].y]; hj[k] = h[v[k].x]; }
        for (int k = 0; k < m; ++k) {
            int id = v[k].y - nodebase;
            float4 a4 = hi[k], b4 = hj[k];
            bool zero = (a4.x == b4.x) && (a4.y == b4.y) && (a4.z == b4.z) && (a4.w == b4.w);
            if (!zero) {
                float z[8], m1[8], z2[4], m2[4];
                z1_of(a4, b4, w1, b1, z);
#pragma unroll
                for (int j = 0; j < 8; ++j) m1[j] = ftanh(z[j] * ss1[j] + ss1[8 + j]);
                mat8x4(m1, w2, b2, z2);
#pragma unroll
                for (int c = 0; c < 4; ++c) m2[c] = ftanh(z2[c] * ss2[c] + ss2[4 + c]);
#pragma unroll
                for (int c = 0; c < 4; ++c) atomicAdd(&lacc[id * 5 + c], m2[c]);
            }
            atomicAdd(&lacc[id * 5 + 4], 1.0f);
        }
    }
    __syncthreads();
    float* pp = part + (size_t)blockIdx.x * (512 * 5);
    for (int k = threadIdx.x; k < 512 * 5; k += 256)
        __builtin_nontemporal_store(lacc[k], pp + k);
}

// ---------------- merge SPLIT partials per node -> acc record ----------------
__global__ __launch_bounds__(256) void k_merge(const float* __restrict__ part, float* __restrict__ acc, int n) {
    int node = blockIdx.x * 256 + threadIdx.x;
    if (node >= n) return;
    int bucket = node >> 9, id = node & 511;
    float v0 = 0.f, v1 = 0.f, v2 = 0.f, v3 = 0.f, v4 = 0.f;
#pragma unroll
    for (int p = 0; p < SPLIT; ++p) {
        const float* pp = part + (size_t)(bucket * SPLIT + p) * (512 * 5) + id * 5;
        v0 += pp[0]; v1 += pp[1]; v2 += pp[2]; v3 += pp[3]; v4 += pp[4];
    }
    float* ap = acc + 8 * (size_t)node;
    ap[0] = v0; ap[1] = v1; ap[2] = v2; ap[3] = v3; ap[4] = v4;
}

// ---------------- fallback edge kernels (round-1 style, used if ws too small) ----------------
__global__ __launch_bounds__(256) void fb_stats1(const int* __restrict__ idx, const float4* __restrict__ h,
                                                 const float* __restrict__ w1, const float* __restrict__ b1,
                                                 float* __restrict__ sums, float* __restrict__ acc, int E_) {
    float a[16];
#pragma unroll
    for (int i = 0; i < 16; ++i) a[i] = 0.f;
    int stride = gridDim.x * blockDim.x;
    for (int e = blockIdx.x * blockDim.x + threadIdx.x; e < E_; e += stride) {
        int s = __builtin_nontemporal_load(idx + e);
        int d = __builtin_nontemporal_load(idx + E_ + e);
        float4 hi = h[d], hj = h[s];
        float z[8];
        z1_of(hi, hj, w1, b1, z);
#pragma unroll
        for (int j = 0; j < 8; ++j) { a[j] += z[j]; a[8 + j] += z[j] * z[j]; }
        atomicAdd(acc + 8 * (size_t)d + 4, 1.0f);
    }
    block_reduce_atomics<16>(a, sums);
}

__global__ __launch_bounds__(256) void fb_stats2(const int* __restrict__ idx, const float4* __restrict__ h,
                                                 const float* __restrict__ w1, const float* __restrict__ b1,
                                                 const float* __restrict__ ss1,
                                                 const float* __restrict__ w2, const float* __restrict__ b2,
                                                 float* __restrict__ sums2, int E_) {
    float a[8];
#pragma unroll
    for (int i = 0; i < 8; ++i) a[i] = 0.f;
    int stride = gridDim.x * blockDim.x;
    for (int e = blockIdx.x * blockDim.x + threadIdx.x; e < E_; e += stride) {
        int s = __builtin_nontemporal_load(idx + e);
        int d = __builtin_nontemporal_load(idx + E_ + e);
        float4 hi = h[d], hj = h[s];
        float z[8], m1[8], z2[4];
        z1_of(hi, hj, w1, b1, z);
#pragma unroll
        for (int j = 0; j < 8; ++j) m1[j] = ftanh(z[j] * ss1[j] + ss1[8 + j]);
        mat8x4(m1, w2, b2, z2);
#pragma unroll
        for (int c = 0; c < 4; ++c) { a[c] += z2[c]; a[4 + c] += z2[c] * z2[c]; }
    }
    block_reduce_atomics<8>(a, sums2);
}

__global__ __launch_bounds__(256) void fb_scatter(const int* __restrict__ idx, const float4* __restrict__ h,
                                                  const float* __restrict__ w1, const float* __restrict__ b1,
                                                  const float* __restrict__ ss1,
                                                  const float* __restrict__ w2, const float* __restrict__ b2,
                                                  const float* __restrict__ ss2,
                                                  float* __restrict__ acc, int E_) {
    int stride = gridDim.x * blockDim.x;
    for (int e = blockIdx.x * blockDim.x + threadIdx.x; e < E_; e += stride) {
        int s = __builtin_nontemporal_load(idx + e);
        int d = __builtin_nontemporal_load(idx + E_ + e);
        float4 hi = h[d], hj = h[s];
        bool zero = (hi.x == hj.x) && (hi.y == hj.y) && (hi.z == hj.z) && (hi.w == hj.w);
        if (zero) continue;
        float z[8], m1[8], z2[4], m2[4];
        z1_of(hi, hj, w1, b1, z);
#pragma unroll
        for (int j = 0; j < 8; ++j) m1[j] = ftanh(z[j] * ss1[j] + ss1[8 + j]);
        mat8x4(m1, w2, b2, z2);
#pragma unroll
        for (int c = 0; c < 4; ++c) m2[c] = ftanh(z2[c] * ss2[c] + ss2[4 + c]);
        float* ap = acc + 8 * (size_t)d;
        atomicAdd(ap + 0, m2[0]);
        atomicAdd(ap + 1, m2[1]);
        atomicAdd(ap + 2, m2[2]);
        atomicAdd(ap + 3, m2[3]);
    }
}

// ---------------- node update MLP ----------------
__device__ __forceinline__ void load_u(int i, const float4* __restrict__ h,
                                       const float* __restrict__ acc, float* u) {
    float4 hv = h[i];
    const float* ap = acc + 8 * (size_t)i;
    float c = fmaxf(ap[4], 1.0f);
    u[0] = hv.x; u[1] = hv.y; u[2] = hv.z; u[3] = hv.w;
    u[4] = ap[0]; u[5] = ap[1]; u[6] = ap[2] / c; u[7] = ap[3] / c;
}

__global__ __launch_bounds__(256) void n_stats1(const float4* __restrict__ h,
                                                const float* __restrict__ acc,
                                                const float* __restrict__ w, const float* __restrict__ b,
                                                float* __restrict__ sums, int n) {
    float a[16];
#pragma unroll
    for (int i = 0; i < 16; ++i) a[i] = 0.f;
    int stride = gridDim.x * blockDim.x;
    for (int i = blockIdx.x * blockDim.x + threadIdx.x; i < n; i += stride) {
        float u[8], z[8];
        load_u(i, h, acc, u);
        mat8x8(u, w, b, z);
#pragma unroll
        for (int j = 0; j < 8; ++j) { a[j] += z[j]; a[8 + j] += z[j] * z[j]; }
    }
    block_reduce_atomics<16>(a, sums);
}

__global__ __launch_bounds__(256) void n_stats2(const float4* __restrict__ h,
                                                const float* __restrict__ acc,
                                                const float* __restrict__ w1, const float* __restrict__ b1,
                                                const float* __restrict__ sums3,
                                                const float* __restrict__ g3, const float* __restrict__ be3,
                                                float invN,
                                                const float* __restrict__ w2, const float* __restrict__ b2,
                                                float* __restrict__ sums, int n) {
    __shared__ float ss3[16];
    fin_lds(sums3, g3, be3, 8, invN, ss3);
    float a[8];
#pragma unroll
    for (int i = 0; i < 8; ++i) a[i] = 0.f;
    int stride = gridDim.x * blockDim.x;
    for (int i = blockIdx.x * blockDim.x + threadIdx.x; i < n; i += stride) {
        float u[8], z[8], u1[8], z4[4];
        load_u(i, h, acc, u);
        mat8x8(u, w1, b1, z);
#pragma unroll
        for (int j = 0; j < 8; ++j) u1[j] = ftanh(z[j] * ss3[j] + ss3[8 + j]);
        mat8x4(u1, w2, b2, z4);
#pragma unroll
        for (int c = 0; c < 4; ++c) { a[c] += z4[c]; a[4 + c] += z4[c] * z4[c]; }
    }
    block_reduce_atomics<8>(a, sums);
}

__global__ __launch_bounds__(256) void n_final(const float4* __restrict__ h,
                                               const float* __restrict__ acc,
                                               const float* __restrict__ w1, const float* __restrict__ b1,
                                               const float* __restrict__ sums3,
                                               const float* __restrict__ g3, const float* __restrict__ be3,
                                               const float* __restrict__ sums4,
                                               const float* __restrict__ g4, const float* __restrict__ be4,
                                               float invN,
                                               const float* __restrict__ w2, const float* __restrict__ b2,
                                               const float* __restrict__ pw, const float* __restrict__ pb,
                                               float2* __restrict__ out, int n) {
    __shared__ float ss3[16];
    __shared__ float ss4[8];
    fin_lds(sums3, g3, be3, 8, invN, ss3);
    fin_lds(sums4, g4, be4, 4, invN, ss4);
    int stride = gridDim.x * blockDim.x;
    for (int i = blockIdx.x * blockDim.x + threadIdx.x; i < n; i += stride) {
        float u[8], z[8], u1[8], z4[4], u2[4];
        load_u(i, h, acc, u);
        mat8x8(u, w1, b1, z);
#pragma unroll
        for (int j = 0; j < 8; ++j) u1[j] = ftanh(z[j] * ss3[j] + ss3[8 + j]);
        mat8x4(u1, w2, b2, z4);
#pragma unroll
        for (int c = 0; c < 4; ++c) u2[c] = ftanh(z4[c] * ss4[c] + ss4[4 + c]);
        float o0 = pb[0] + u2[0] * pw[0] + u2[1] * pw[2] + u2[2] * pw[4] + u2[3] * pw[6];
        float o1 = pb[1] + u2[0] * pw[1] + u2[1] * pw[3] + u2[2] * pw[5] + u2[3] * pw[7];
        out[i] = make_float2(o0, o1);
    }
}

extern "C" void kernel_launch(void* const* d_in, const int* in_sizes, int n_in,
                              void* d_out, int out_size, void* d_ws, size_t ws_size,
                              hipStream_t stream) {
    const float* pos  = (const float*)d_in[0];
    const float* vel  = (const float*)d_in[1];
    const int*   eidx = (const int*)d_in[2];
    const float* lin_w = (const float*)d_in[3];
    const float* lin_b = (const float*)d_in[4];
    const float* mw1 = (const float*)d_in[5];
    const float* mb1 = (const float*)d_in[6];
    const float* mg1 = (const float*)d_in[7];
    const float* mbe1 = (const float*)d_in[8];
    const float* mw2 = (const float*)d_in[9];
    const float* mb2 = (const float*)d_in[10];
    const float* mg2 = (const float*)d_in[11];
    const float* mbe2 = (const float*)d_in[12];
    const float* uw1 = (const float*)d_in[13];
    const float* ub1 = (const float*)d_in[14];
    const float* ug1 = (const float*)d_in[15];
    const float* ube1 = (const float*)d_in[16];
    const float* uw2 = (const float*)d_in[17];
    const float* ub2 = (const float*)d_in[18];
    const float* ug2 = (const float*)d_in[19];
    const float* ube2 = (const float*)d_in[20];
    const float* pw = (const float*)d_in[21];
    const float* pb = (const float*)d_in[22];

    int n  = in_sizes[0] / 2;
    int E_ = in_sizes[2] / 2;
    float invE = 1.0f / (float)E_;
    float invN = 1.0f / (float)n;

    // ---- workspace layout (bump allocator, 16B aligned) ----
    char* base = (char*)d_ws;
    size_t off = 0;
    auto alloc = [&](size_t bytes) {
        off = (off + 15) & ~(size_t)15;
        void* p = base + off;
        off += bytes;
        return p;
    };
    int nbuckets = (n + 511) >> 9;
    float4* h      = (float4*)alloc(16 * (size_t)n);                 // 4 MB
    float*  acc    = (float*)alloc(32 * (size_t)n);                  // 8 MB
    float*  sums   = (float*)alloc(512);
    float*  ss     = sums + 64;
    uint32* bbase  = (uint32*)alloc(4 * (NB + 1));
    uint32* rowtot = (uint32*)alloc(4 * NB);
    uint32* cntmat = (uint32*)alloc(4 * (size_t)NB * GB);            // 1 MB
    float*  part   = (float*)alloc(4 * (size_t)nbuckets * SPLIT * 512 * 5); // ~40 MB
    vi2*    sp     = (vi2*)alloc(8 * (size_t)E_);                    // 64 MB
    size_t need_sort = off;                                           // ~118 MB

    bool big = ws_size >= need_sort;

    int nblk = (n + 255) / 256;
    int T = (E_ + GB - 1) / GB;

    k_h<<<nblk, 256, 0, stream>>>(pos, vel, lin_w, lin_b, h, n);

    if (big) {
        (void)hipMemsetAsync(sums, 0, 256, stream);   // zero the 64 accumulator floats

        k_cnt<<<GB, 256, 0, stream>>>(eidx + E_, cntmat, E_, T);
        k_scanA<<<NB, 256, 0, stream>>>(cntmat, rowtot);
        k_scanB<<<1, 256, 0, stream>>>(rowtot, bbase);

        k_reorder<<<GB, 256, 0, stream>>>(eidx, cntmat, bbase, sp, E_, T);

        e_stats1<<<2048, 256, 0, stream>>>(sp, h, mw1, mb1, sums, E_);

        e_pass2<<<2048, 256, 0, stream>>>(sp, h, mw1, mb1, sums, mg1, mbe1, invE,
                                          mw2, mb2, sums + 16, E_);

        e_aggr_part<<<nbuckets * SPLIT, 256, 0, stream>>>(sp, h, bbase, rowtot,
                                                          mw1, mb1, sums, mg1, mbe1,
                                                          sums + 16, mg2, mbe2, invE,
                                                          mw2, mb2, part);
        k_merge<<<nblk, 256, 0, stream>>>(part, acc, n);

        n_stats1<<<nblk, 256, 0, stream>>>(h, acc, uw1, ub1, sums + 24, n);
        n_stats2<<<nblk, 256, 0, stream>>>(h, acc, uw1, ub1, sums + 24, ug1, ube1, invN,
                                           uw2, ub2, sums + 40, n);
        n_final<<<nblk, 256, 0, stream>>>(h, acc, uw1, ub1, sums + 24, ug1, ube1,
                                          sums + 40, ug2, ube2, invN,
                                          uw2, ub2, pw, pb, (float2*)d_out, n);
    } else {
        (void)hipMemsetAsync(acc, 0, 32 * (size_t)n + 256, stream);

        fb_stats1<<<4096, 256, 0, stream>>>(eidx, h, mw1, mb1, sums, acc, E_);
        k_fin<<<1, 64, 0, stream>>>(sums, ss, mg1, mbe1, 8, invE);

        fb_stats2<<<4096, 256, 0, stream>>>(eidx, h, mw1, mb1, ss, mw2, mb2, sums + 16, E_);
        k_fin<<<1, 64, 0, stream>>>(sums + 16, ss + 16, mg2, mbe2, 4, invE);

        fb_scatter<<<4096, 256, 0, stream>>>(eidx, h, mw1, mb1, ss, mw2, mb2, ss + 16, acc, E_);

        n_stats1<<<nblk, 256, 0, stream>>>(h, acc, uw1, ub1, sums + 24, n);
        n_stats2<<<nblk, 256, 0, stream>>>(h, acc, uw1, ub1, sums + 24, ug1, ube1, invN,
                                           uw2, ub2, sums + 40, n);
        n_final<<<nblk, 256, 0, stream>>>(h, acc, uw1, ub1, sums + 24, ug1, ube1,
                                          sums + 40, ug2, ube2, invN,
                                          uw2, ub2, pw, pb, (float2*)d_out, n);
    }
}

// Round 13
// 576.273 us; speedup vs baseline: 1.1649x; 1.1526x over previous
//
#include <hip/hip_runtime.h>

#define EPSBN 1e-5f
#define NB 512            // buckets (dst >> 9), 512 nodes per bucket
#define GB 512            // blocks for cnt/reorder tiles
#define SPLIT 8           // blocks per bucket in e_aggr

typedef float vf4 __attribute__((ext_vector_type(4)));
typedef int   vi2 __attribute__((ext_vector_type(2)));
typedef int   vi4 __attribute__((ext_vector_type(4)));
typedef unsigned int uint32;

__device__ __forceinline__ float ftanh(float x) {
    return 1.0f - 2.0f / (__expf(2.0f * x) + 1.0f);
}

__device__ __forceinline__ float wave_sum(float v) {
#pragma unroll
    for (int off = 32; off > 0; off >>= 1) v += __shfl_down(v, off);
    return v;
}

__device__ __forceinline__ void z1_of(const float4 hi, const float4 hj,
                                      const float* __restrict__ w, const float* __restrict__ b,
                                      float* z) {
#pragma unroll
    for (int j = 0; j < 8; ++j) {
        z[j] = b[j]
             + hi.x * w[0 * 8 + j] + hi.y * w[1 * 8 + j] + hi.z * w[2 * 8 + j] + hi.w * w[3 * 8 + j]
             + hj.x * w[4 * 8 + j] + hj.y * w[5 * 8 + j] + hj.z * w[6 * 8 + j] + hj.w * w[7 * 8 + j];
    }
}

__device__ __forceinline__ void mat8x4(const float* u, const float* __restrict__ w,
                                       const float* __restrict__ b, float* z) {
#pragma unroll
    for (int c = 0; c < 4; ++c) {
        float t = b[c];
#pragma unroll
        for (int k = 0; k < 8; ++k) t += u[k] * w[k * 4 + c];
        z[c] = t;
    }
}

__device__ __forceinline__ void mat8x8(const float* u, const float* __restrict__ w,
                                       const float* __restrict__ b, float* z) {
#pragma unroll
    for (int j = 0; j < 8; ++j) {
        float t = b[j];
#pragma unroll
        for (int k = 0; k < 8; ++k) t += u[k] * w[k * 8 + j];
        z[j] = t;
    }
}

template <int NV>
__device__ __forceinline__ void block_reduce_atomics(float* a, float* __restrict__ sums) {
    __shared__ float red[NV * 4];
    int wid = threadIdx.x >> 6, lane = threadIdx.x & 63;
#pragma unroll
    for (int i = 0; i < NV; ++i) {
        float v = wave_sum(a[i]);
        if (lane == 0) red[i * 4 + wid] = v;
    }
    __syncthreads();
    if (threadIdx.x < NV) {
        float v = red[threadIdx.x * 4 + 0] + red[threadIdx.x * 4 + 1]
                + red[threadIdx.x * 4 + 2] + red[threadIdx.x * 4 + 3];
        atomicAdd(&sums[threadIdx.x], v);
    }
}

// compute BN scale/shift into LDS from raw sums (call with all threads; syncs inside)
__device__ __forceinline__ void fin_lds(const float* __restrict__ sums,
                                        const float* __restrict__ g, const float* __restrict__ be,
                                        int d, float inv, float* out) {
    int j = threadIdx.x;
    if (j < d) {
        float mu = sums[j] * inv;
        float var = sums[d + j] * inv - mu * mu;
        float s = g[j] * rsqrtf(var + EPSBN);
        out[j] = s;
        out[d + j] = be[j] - mu * s;
    }
    __syncthreads();
}

// per-edge z1-stats accumulate (all arrays constant-indexed after inline+unroll)
__device__ __forceinline__ void stats1_edge(float4 hi, float4 hj,
                                            const float* __restrict__ w1, const float* __restrict__ b1,
                                            float* a) {
    float z[8];
    z1_of(hi, hj, w1, b1, z);
#pragma unroll
    for (int j = 0; j < 8; ++j) { a[j] += z[j]; a[8 + j] += z[j] * z[j]; }
}

// per-edge z2-stats accumulate
__device__ __forceinline__ void stats2_edge(float4 hi, float4 hj,
                                            const float* __restrict__ w1, const float* __restrict__ b1,
                                            const float* ss1,
                                            const float* __restrict__ w2, const float* __restrict__ b2,
                                            float* a) {
    float z[8], m1[8], z2[4];
    z1_of(hi, hj, w1, b1, z);
#pragma unroll
    for (int j = 0; j < 8; ++j) m1[j] = ftanh(z[j] * ss1[j] + ss1[8 + j]);
    mat8x4(m1, w2, b2, z2);
#pragma unroll
    for (int c = 0; c < 4; ++c) { a[c] += z2[c]; a[4 + c] += z2[c] * z2[c]; }
}

// per-edge full message -> LDS accumulate
__device__ __forceinline__ void aggr_edge(float4 hi, float4 hj, int id,
                                          const float* __restrict__ w1, const float* __restrict__ b1,
                                          const float* ss1,
                                          const float* __restrict__ w2, const float* __restrict__ b2,
                                          const float* ss2, float* lacc) {
    bool zero = (hi.x == hj.x) && (hi.y == hj.y) && (hi.z == hj.z) && (hi.w == hj.w);
    if (!zero) {
        float z[8], m1[8], z2[4], m2[4];
        z1_of(hi, hj, w1, b1, z);
#pragma unroll
        for (int j = 0; j < 8; ++j) m1[j] = ftanh(z[j] * ss1[j] + ss1[8 + j]);
        mat8x4(m1, w2, b2, z2);
#pragma unroll
        for (int c = 0; c < 4; ++c) m2[c] = ftanh(z2[c] * ss2[c] + ss2[4 + c]);
#pragma unroll
        for (int c = 0; c < 4; ++c) atomicAdd(&lacc[id * 5 + c], m2[c]);
    }
    atomicAdd(&lacc[id * 5 + 4], 1.0f);
}

// ---------------- node input projection ----------------
__global__ __launch_bounds__(256) void k_h(const float* __restrict__ pos, const float* __restrict__ vel,
                                           const float* __restrict__ w, const float* __restrict__ b,
                                           float4* __restrict__ h, int n) {
    int i = blockIdx.x * blockDim.x + threadIdx.x;
    if (i >= n) return;
    float2 p = ((const float2*)pos)[i];
    float2 v = ((const float2*)vel)[i];
    float o[4];
#pragma unroll
    for (int d = 0; d < 4; ++d)
        o[d] = b[d] + p.x * w[0 * 4 + d] + p.y * w[1 * 4 + d] + v.x * w[2 * 4 + d] + v.y * w[3 * 4 + d];
    h[i] = make_float4(o[0], o[1], o[2], o[3]);
}

// ---------------- count: per-(block,bucket) histogram ----------------
__global__ __launch_bounds__(256) void k_cnt(const int* __restrict__ dst, uint32* __restrict__ cntmat,
                                             int E_, int T) {
    __shared__ uint32 hist[NB];
    for (int b = threadIdx.x; b < NB; b += 256) hist[b] = 0;
    __syncthreads();
    int lo = blockIdx.x * T, hi2 = min(E_, lo + T);
    for (int e0 = lo + 4 * threadIdx.x; e0 < hi2; e0 += 1024) {
        int m = min(4, hi2 - e0);
        if (m == 4) {
            int d0 = __builtin_nontemporal_load(dst + e0);
            int d1 = __builtin_nontemporal_load(dst + e0 + 1);
            int d2 = __builtin_nontemporal_load(dst + e0 + 2);
            int d3 = __builtin_nontemporal_load(dst + e0 + 3);
            atomicAdd(&hist[d0 >> 9], 1u);
            atomicAdd(&hist[d1 >> 9], 1u);
            atomicAdd(&hist[d2 >> 9], 1u);
            atomicAdd(&hist[d3 >> 9], 1u);
        } else {
            for (int k = 0; k < m; ++k) {
                int d = __builtin_nontemporal_load(dst + e0 + k);
                atomicAdd(&hist[d >> 9], 1u);
            }
        }
    }
    __syncthreads();
    for (int b = threadIdx.x; b < NB; b += 256)
        cntmat[(size_t)b * GB + blockIdx.x] = hist[b];
}

// block-scan of 512 uints (256 threads x 2), exclusive
__device__ __forceinline__ void scan512(uint32* v, uint32* excl_out, uint32* total) {
    __shared__ uint32 ts[256];
    uint32 local = v[0] + v[1];
    ts[threadIdx.x] = local;
    __syncthreads();
    for (int off = 1; off < 256; off <<= 1) {
        uint32 t = (threadIdx.x >= (uint32)off) ? ts[threadIdx.x - off] : 0u;
        __syncthreads();
        ts[threadIdx.x] += t;
        __syncthreads();
    }
    *excl_out = ts[threadIdx.x] - local;
    *total = ts[255];
}

__global__ __launch_bounds__(256) void k_scanA(uint32* __restrict__ cntmat, uint32* __restrict__ rowtot) {
    size_t base = (size_t)blockIdx.x * GB + threadIdx.x * 2;
    uint32 v[2];
    v[0] = cntmat[base]; v[1] = cntmat[base + 1];
    uint32 excl, tot;
    scan512(v, &excl, &tot);
    cntmat[base] = excl;
    cntmat[base + 1] = excl + v[0];
    if (threadIdx.x == 0) rowtot[blockIdx.x] = tot;
}

__global__ __launch_bounds__(256) void k_scanB(const uint32* __restrict__ rowtot, uint32* __restrict__ bbase) {
    uint32 v[2];
    v[0] = rowtot[threadIdx.x * 2]; v[1] = rowtot[threadIdx.x * 2 + 1];
    uint32 excl, tot;
    scan512(v, &excl, &tot);
    bbase[threadIdx.x * 2] = excl;
    bbase[threadIdx.x * 2 + 1] = excl + v[0];
    if (threadIdx.x == 0) bbase[NB] = tot;
}

// ---------------- reorder: pure 8B scatter, 4-edge batches (no h, no stats) ----------------
__global__ __launch_bounds__(256) void k_reorder(const int* __restrict__ idx,
                                                 const uint32* __restrict__ cntmat, const uint32* __restrict__ bbase,
                                                 vi2* __restrict__ sp, int E_, int T) {
    __shared__ uint32 cur[NB];
    for (int b = threadIdx.x; b < NB; b += 256)
        cur[b] = bbase[b] + cntmat[(size_t)b * GB + blockIdx.x];
    __syncthreads();
    int lo = blockIdx.x * T, hi2 = min(E_, lo + T);
    for (int e0 = lo + 4 * threadIdx.x; e0 < hi2; e0 += 1024) {
        int m = min(4, hi2 - e0);
        if (m == 4) {
            int s0 = __builtin_nontemporal_load(idx + e0);
            int s1 = __builtin_nontemporal_load(idx + e0 + 1);
            int s2 = __builtin_nontemporal_load(idx + e0 + 2);
            int s3 = __builtin_nontemporal_load(idx + e0 + 3);
            int d0 = __builtin_nontemporal_load(idx + E_ + e0);
            int d1 = __builtin_nontemporal_load(idx + E_ + e0 + 1);
            int d2 = __builtin_nontemporal_load(idx + E_ + e0 + 2);
            int d3 = __builtin_nontemporal_load(idx + E_ + e0 + 3);
            uint32 p0 = atomicAdd(&cur[d0 >> 9], 1u);
            uint32 p1 = atomicAdd(&cur[d1 >> 9], 1u);
            uint32 p2 = atomicAdd(&cur[d2 >> 9], 1u);
            uint32 p3 = atomicAdd(&cur[d3 >> 9], 1u);
            vi2 v0 = {s0, d0}; sp[p0] = v0;
            vi2 v1 = {s1, d1}; sp[p1] = v1;
            vi2 v2 = {s2, d2}; sp[p2] = v2;
            vi2 v3 = {s3, d3}; sp[p3] = v3;
        } else {
            for (int k = 0; k < m; ++k) {
                int s = __builtin_nontemporal_load(idx + e0 + k);
                int d = __builtin_nontemporal_load(idx + E_ + e0 + k);
                uint32 pos = atomicAdd(&cur[d >> 9], 1u);
                vi2 v = {s, d};
                sp[pos] = v;
            }
        }
    }
}

// ---------------- finalize BN stats -> scale/shift (fallback path only) ----------------
__global__ void k_fin(const float* __restrict__ sums, float* __restrict__ ss,
                      const float* __restrict__ g, const float* __restrict__ be,
                      int d, float inv_count) {
    int j = threadIdx.x;
    if (j >= d) return;
    float mu = sums[j] * inv_count;
    float var = sums[d + j] * inv_count - mu * mu;
    float s = g[j] * rsqrtf(var + EPSBN);
    ss[j] = s;
    ss[d + j] = be[j] - mu * s;
}

// ---------------- E-stats1: 4-edge batches over sorted sp (named vars only) ----------------
__global__ __launch_bounds__(256) void e_stats1(const vi2* __restrict__ sp, const float4* __restrict__ h,
                                                const float* __restrict__ w1, const float* __restrict__ b1,
                                                float* __restrict__ sums, int E_) {
    float a[16];
#pragma unroll
    for (int i = 0; i < 16; ++i) a[i] = 0.f;
    int stride4 = gridDim.x * blockDim.x * 4;
    for (int e0 = (blockIdx.x * blockDim.x + threadIdx.x) * 4; e0 < E_; e0 += stride4) {
        int m = min(4, E_ - e0);
        if (m == 4) {
            vi4 A = __builtin_nontemporal_load((const vi4*)(sp + e0));
            vi4 B = __builtin_nontemporal_load((const vi4*)(sp + e0 + 2));
            float4 hi0 = h[A.y], hj0 = h[A.x];
            float4 hi1 = h[A.w], hj1 = h[A.z];
            float4 hi2 = h[B.y], hj2 = h[B.x];
            float4 hi3 = h[B.w], hj3 = h[B.z];
            stats1_edge(hi0, hj0, w1, b1, a);
            stats1_edge(hi1, hj1, w1, b1, a);
            stats1_edge(hi2, hj2, w1, b1, a);
            stats1_edge(hi3, hj3, w1, b1, a);
        } else {
            for (int k = 0; k < m; ++k) {
                vi2 v = __builtin_nontemporal_load(&sp[e0 + k]);
                float4 hi = h[v.y], hj = h[v.x];
                stats1_edge(hi, hj, w1, b1, a);
            }
        }
    }
    block_reduce_atomics<16>(a, sums);
}

// ---------------- E2: 4-edge batches -> z2 stats (named vars only) ----------------
__global__ __launch_bounds__(256) void e_pass2(const vi2* __restrict__ sp, const float4* __restrict__ h,
                                               const float* __restrict__ w1, const float* __restrict__ b1,
                                               const float* __restrict__ sums1,
                                               const float* __restrict__ g1, const float* __restrict__ be1,
                                               float invE,
                                               const float* __restrict__ w2, const float* __restrict__ b2,
                                               float* __restrict__ sums2, int E_) {
    __shared__ float ss1[16];
    fin_lds(sums1, g1, be1, 8, invE, ss1);
    float a[8];
#pragma unroll
    for (int i = 0; i < 8; ++i) a[i] = 0.f;
    int stride4 = gridDim.x * blockDim.x * 4;
    for (int e0 = (blockIdx.x * blockDim.x + threadIdx.x) * 4; e0 < E_; e0 += stride4) {
        int m = min(4, E_ - e0);
        if (m == 4) {
            vi4 A = __builtin_nontemporal_load((const vi4*)(sp + e0));
            vi4 B = __builtin_nontemporal_load((const vi4*)(sp + e0 + 2));
            float4 hi0 = h[A.y], hj0 = h[A.x];
            float4 hi1 = h[A.w], hj1 = h[A.z];
            float4 hi2 = h[B.y], hj2 = h[B.x];
            float4 hi3 = h[B.w], hj3 = h[B.z];
            stats2_edge(hi0, hj0, w1, b1, ss1, w2, b2, a);
            stats2_edge(hi1, hj1, w1, b1, ss1, w2, b2, a);
            stats2_edge(hi2, hj2, w1, b1, ss1, w2, b2, a);
            stats2_edge(hi3, hj3, w1, b1, ss1, w2, b2, a);
        } else {
            for (int k = 0; k < m; ++k) {
                vi2 v = __builtin_nontemporal_load(&sp[e0 + k]);
                float4 hi = h[v.y], hj = h[v.x];
                stats2_edge(hi, hj, w1, b1, ss1, w2, b2, a);
            }
        }
    }
    block_reduce_atomics<8>(a, sums2);
}

// ---------------- aggregate: SPLIT blocks per bucket; 4-edge named-var pipeline ----------------
__global__ __launch_bounds__(256) void e_aggr_part(const vi2* __restrict__ sp, const float4* __restrict__ h,
                                                   const uint32* __restrict__ bbase, const uint32* __restrict__ rowtot,
                                                   const float* __restrict__ w1, const float* __restrict__ b1,
                                                   const float* __restrict__ sums1,
                                                   const float* __restrict__ g1, const float* __restrict__ be1,
                                                   const float* __restrict__ sums2,
                                                   const float* __restrict__ g2, const float* __restrict__ be2,
                                                   float invE,
                                                   const float* __restrict__ w2, const float* __restrict__ b2,
                                                   float* __restrict__ part) {
    __shared__ float lacc[512 * 5];
    __shared__ float ss1[16];
    __shared__ float ss2[8];
    fin_lds(sums1, g1, be1, 8, invE, ss1);
    fin_lds(sums2, g2, be2, 4, invE, ss2);
    int bucket = blockIdx.x >> 3;          // / SPLIT
    int pi = blockIdx.x & (SPLIT - 1);
    int nodebase = bucket << 9;
    for (int k = threadIdx.x; k < 512 * 5; k += 256) lacc[k] = 0.f;
    __syncthreads();
    uint32 start = bbase[bucket];
    uint32 len = rowtot[bucket];
    uint32 chunk = (len + SPLIT - 1) / SPLIT;
    uint32 s0 = start + (uint32)pi * chunk;
    uint32 s1 = min(start + len, s0 + chunk);

    for (uint32 e0 = s0 + 4 * threadIdx.x; e0 < s1; e0 += 1024) {
        int m = (int)min(4u, s1 - e0);
        if (m == 4) {
            // all 4 sp loads, then all 8 gathers, all in named registers
            vi2 v0 = __builtin_nontemporal_load(&sp[e0]);
            vi2 v1 = __builtin_nontemporal_load(&sp[e0 + 1]);
            vi2 v2 = __builtin_nontemporal_load(&sp[e0 + 2]);
            vi2 v3 = __builtin_nontemporal_load(&sp[e0 + 3]);
            float4 hi0 = h[v0.y], hj0 = h[v0.x];
            float4 hi1 = h[v1.y], hj1 = h[v1.x];
            float4 hi2 = h[v2.y], hj2 = h[v2.x];
            float4 hi3 = h[v3.y], hj3 = h[v3.x];
            aggr_edge(hi0, hj0, v0.y - nodebase, w1, b1, ss1, w2, b2, ss2, lacc);
            aggr_edge(hi1, hj1, v1.y - nodebase, w1, b1, ss1, w2, b2, ss2, lacc);
            aggr_edge(hi2, hj2, v2.y - nodebase, w1, b1, ss1, w2, b2, ss2, lacc);
            aggr_edge(hi3, hj3, v3.y - nodebase, w1, b1, ss1, w2, b2, ss2, lacc);
        } else {
            for (int k = 0; k < m; ++k) {
                vi2 v = __builtin_nontemporal_load(&sp[e0 + k]);
                float4 hi = h[v.y], hj = h[v.x];
                aggr_edge(hi, hj, v.y - nodebase, w1, b1, ss1, w2, b2, ss2, lacc);
            }
        }
    }
    __syncthreads();
    float* pp = part + (size_t)blockIdx.x * (512 * 5);
    for (int k = threadIdx.x; k < 512 * 5; k += 256)
        __builtin_nontemporal_store(lacc[k], pp + k);
}

// ---------------- merge SPLIT partials per node -> acc record ----------------
__global__ __launch_bounds__(256) void k_merge(const float* __restrict__ part, float* __restrict__ acc, int n) {
    int node = blockIdx.x * 256 + threadIdx.x;
    if (node >= n) return;
    int bucket = node >> 9, id = node & 511;
    float v0 = 0.f, v1 = 0.f, v2 = 0.f, v3 = 0.f, v4 = 0.f;
#pragma unroll
    for (int p = 0; p < SPLIT; ++p) {
        const float* pp = part + (size_t)(bucket * SPLIT + p) * (512 * 5) + id * 5;
        v0 += pp[0]; v1 += pp[1]; v2 += pp[2]; v3 += pp[3]; v4 += pp[4];
    }
    float* ap = acc + 8 * (size_t)node;
    ap[0] = v0; ap[1] = v1; ap[2] = v2; ap[3] = v3; ap[4] = v4;
}

// ---------------- fallback edge kernels (round-1 style, used if ws too small) ----------------
__global__ __launch_bounds__(256) void fb_stats1(const int* __restrict__ idx, const float4* __restrict__ h,
                                                 const float* __restrict__ w1, const float* __restrict__ b1,
                                                 float* __restrict__ sums, float* __restrict__ acc, int E_) {
    float a[16];
#pragma unroll
    for (int i = 0; i < 16; ++i) a[i] = 0.f;
    int stride = gridDim.x * blockDim.x;
    for (int e = blockIdx.x * blockDim.x + threadIdx.x; e < E_; e += stride) {
        int s = __builtin_nontemporal_load(idx + e);
        int d = __builtin_nontemporal_load(idx + E_ + e);
        float4 hi = h[d], hj = h[s];
        stats1_edge(hi, hj, w1, b1, a);
        atomicAdd(acc + 8 * (size_t)d + 4, 1.0f);
    }
    block_reduce_atomics<16>(a, sums);
}

__global__ __launch_bounds__(256) void fb_stats2(const int* __restrict__ idx, const float4* __restrict__ h,
                                                 const float* __restrict__ w1, const float* __restrict__ b1,
                                                 const float* __restrict__ ss1,
                                                 const float* __restrict__ w2, const float* __restrict__ b2,
                                                 float* __restrict__ sums2, int E_) {
    float a[8];
#pragma unroll
    for (int i = 0; i < 8; ++i) a[i] = 0.f;
    int stride = gridDim.x * blockDim.x;
    for (int e = blockIdx.x * blockDim.x + threadIdx.x; e < E_; e += stride) {
        int s = __builtin_nontemporal_load(idx + e);
        int d = __builtin_nontemporal_load(idx + E_ + e);
        float4 hi = h[d], hj = h[s];
        stats2_edge(hi, hj, w1, b1, ss1, w2, b2, a);
    }
    block_reduce_atomics<8>(a, sums2);
}

__global__ __launch_bounds__(256) void fb_scatter(const int* __restrict__ idx, const float4* __restrict__ h,
                                                  const float* __restrict__ w1, const float* __restrict__ b1,
                                                  const float* __restrict__ ss1,
                                                  const float* __restrict__ w2, const float* __restrict__ b2,
                                                  const float* __restrict__ ss2,
                                                  float* __restrict__ acc, int E_) {
    int stride = gridDim.x * blockDim.x;
    for (int e = blockIdx.x * blockDim.x + threadIdx.x; e < E_; e += stride) {
        int s = __builtin_nontemporal_load(idx + e);
        int d = __builtin_nontemporal_load(idx + E_ + e);
        float4 hi = h[d], hj = h[s];
        bool zero = (hi.x == hj.x) && (hi.y == hj.y) && (hi.z == hj.z) && (hi.w == hj.w);
        if (zero) continue;
        float z[8], m1[8], z2[4], m2[4];
        z1_of(hi, hj, w1, b1, z);
#pragma unroll
        for (int j = 0; j < 8; ++j) m1[j] = ftanh(z[j] * ss1[j] + ss1[8 + j]);
        mat8x4(m1, w2, b2, z2);
#pragma unroll
        for (int c = 0; c < 4; ++c) m2[c] = ftanh(z2[c] * ss2[c] + ss2[4 + c]);
        float* ap = acc + 8 * (size_t)d;
        atomicAdd(ap + 0, m2[0]);
        atomicAdd(ap + 1, m2[1]);
        atomicAdd(ap + 2, m2[2]);
        atomicAdd(ap + 3, m2[3]);
    }
}

// ---------------- node update MLP ----------------
__device__ __forceinline__ void load_u(int i, const float4* __restrict__ h,
                                       const float* __restrict__ acc, float* u) {
    float4 hv = h[i];
    const float* ap = acc + 8 * (size_t)i;
    float c = fmaxf(ap[4], 1.0f);
    u[0] = hv.x; u[1] = hv.y; u[2] = hv.z; u[3] = hv.w;
    u[4] = ap[0]; u[5] = ap[1]; u[6] = ap[2] / c; u[7] = ap[3] / c;
}

__global__ __launch_bounds__(256) void n_stats1(const float4* __restrict__ h,
                                                const float* __restrict__ acc,
                                                const float* __restrict__ w, const float* __restrict__ b,
                                                float* __restrict__ sums, int n) {
    float a[16];
#pragma unroll
    for (int i = 0; i < 16; ++i) a[i] = 0.f;
    int stride = gridDim.x * blockDim.x;
    for (int i = blockIdx.x * blockDim.x + threadIdx.x; i < n; i += stride) {
        float u[8], z[8];
        load_u(i, h, acc, u);
        mat8x8(u, w, b, z);
#pragma unroll
        for (int j = 0; j < 8; ++j) { a[j] += z[j]; a[8 + j] += z[j] * z[j]; }
    }
    block_reduce_atomics<16>(a, sums);
}

__global__ __launch_bounds__(256) void n_stats2(const float4* __restrict__ h,
                                                const float* __restrict__ acc,
                                                const float* __restrict__ w1, const float* __restrict__ b1,
                                                const float* __restrict__ sums3,
                                                const float* __restrict__ g3, const float* __restrict__ be3,
                                                float invN,
                                                const float* __restrict__ w2, const float* __restrict__ b2,
                                                float* __restrict__ sums, int n) {
    __shared__ float ss3[16];
    fin_lds(sums3, g3, be3, 8, invN, ss3);
    float a[8];
#pragma unroll
    for (int i = 0; i < 8; ++i) a[i] = 0.f;
    int stride = gridDim.x * blockDim.x;
    for (int i = blockIdx.x * blockDim.x + threadIdx.x; i < n; i += stride) {
        float u[8], z[8], u1[8], z4[4];
        load_u(i, h, acc, u);
        mat8x8(u, w1, b1, z);
#pragma unroll
        for (int j = 0; j < 8; ++j) u1[j] = ftanh(z[j] * ss3[j] + ss3[8 + j]);
        mat8x4(u1, w2, b2, z4);
#pragma unroll
        for (int c = 0; c < 4; ++c) { a[c] += z4[c]; a[4 + c] += z4[c] * z4[c]; }
    }
    block_reduce_atomics<8>(a, sums);
}

__global__ __launch_bounds__(256) void n_final(const float4* __restrict__ h,
                                               const float* __restrict__ acc,
                                               const float* __restrict__ w1, const float* __restrict__ b1,
                                               const float* __restrict__ sums3,
                                               const float* __restrict__ g3, const float* __restrict__ be3,
                                               const float* __restrict__ sums4,
                                               const float* __restrict__ g4, const float* __restrict__ be4,
                                               float invN,
                                               const float* __restrict__ w2, const float* __restrict__ b2,
                                               const float* __restrict__ pw, const float* __restrict__ pb,
                                               float2* __restrict__ out, int n) {
    __shared__ float ss3[16];
    __shared__ float ss4[8];
    fin_lds(sums3, g3, be3, 8, invN, ss3);
    fin_lds(sums4, g4, be4, 4, invN, ss4);
    int stride = gridDim.x * blockDim.x;
    for (int i = blockIdx.x * blockDim.x + threadIdx.x; i < n; i += stride) {
        float u[8], z[8], u1[8], z4[4], u2[4];
        load_u(i, h, acc, u);
        mat8x8(u, w1, b1, z);
#pragma unroll
        for (int j = 0; j < 8; ++j) u1[j] = ftanh(z[j] * ss3[j] + ss3[8 + j]);
        mat8x4(u1, w2, b2, z4);
#pragma unroll
        for (int c = 0; c < 4; ++c) u2[c] = ftanh(z4[c] * ss4[c] + ss4[4 + c]);
        float o0 = pb[0] + u2[0] * pw[0] + u2[1] * pw[2] + u2[2] * pw[4] + u2[3] * pw[6];
        float o1 = pb[1] + u2[0] * pw[1] + u2[1] * pw[3] + u2[2] * pw[5] + u2[3] * pw[7];
        out[i] = make_float2(o0, o1);
    }
}

extern "C" void kernel_launch(void* const* d_in, const int* in_sizes, int n_in,
                              void* d_out, int out_size, void* d_ws, size_t ws_size,
                              hipStream_t stream) {
    const float* pos  = (const float*)d_in[0];
    const float* vel  = (const float*)d_in[1];
    const int*   eidx = (const int*)d_in[2];
    const float* lin_w = (const float*)d_in[3];
    const float* lin_b = (const float*)d_in[4];
    const float* mw1 = (const float*)d_in[5];
    const float* mb1 = (const float*)d_in[6];
    const float* mg1 = (const float*)d_in[7];
    const float* mbe1 = (const float*)d_in[8];
    const float* mw2 = (const float*)d_in[9];
    const float* mb2 = (const float*)d_in[10];
    const float* mg2 = (const float*)d_in[11];
    const float* mbe2 = (const float*)d_in[12];
    const float* uw1 = (const float*)d_in[13];
    const float* ub1 = (const float*)d_in[14];
    const float* ug1 = (const float*)d_in[15];
    const float* ube1 = (const float*)d_in[16];
    const float* uw2 = (const float*)d_in[17];
    const float* ub2 = (const float*)d_in[18];
    const float* ug2 = (const float*)d_in[19];
    const float* ube2 = (const float*)d_in[20];
    const float* pw = (const float*)d_in[21];
    const float* pb = (const float*)d_in[22];

    int n  = in_sizes[0] / 2;
    int E_ = in_sizes[2] / 2;
    float invE = 1.0f / (float)E_;
    float invN = 1.0f / (float)n;

    // ---- workspace layout (bump allocator, 16B aligned) ----
    char* base = (char*)d_ws;
    size_t off = 0;
    auto alloc = [&](size_t bytes) {
        off = (off + 15) & ~(size_t)15;
        void* p = base + off;
        off += bytes;
        return p;
    };
    int nbuckets = (n + 511) >> 9;
    float4* h      = (float4*)alloc(16 * (size_t)n);                 // 4 MB
    float*  acc    = (float*)alloc(32 * (size_t)n);                  // 8 MB
    float*  sums   = (float*)alloc(512);
    float*  ss     = sums + 64;
    uint32* bbase  = (uint32*)alloc(4 * (NB + 1));
    uint32* rowtot = (uint32*)alloc(4 * NB);
    uint32* cntmat = (uint32*)alloc(4 * (size_t)NB * GB);            // 1 MB
    float*  part   = (float*)alloc(4 * (size_t)nbuckets * SPLIT * 512 * 5); // ~40 MB
    vi2*    sp     = (vi2*)alloc(8 * (size_t)E_);                    // 64 MB
    size_t need_sort = off;                                           // ~118 MB

    bool big = ws_size >= need_sort;

    int nblk = (n + 255) / 256;
    int T = (E_ + GB - 1) / GB;

    k_h<<<nblk, 256, 0, stream>>>(pos, vel, lin_w, lin_b, h, n);

    if (big) {
        (void)hipMemsetAsync(sums, 0, 256, stream);   // zero the 64 accumulator floats

        k_cnt<<<GB, 256, 0, stream>>>(eidx + E_, cntmat, E_, T);
        k_scanA<<<NB, 256, 0, stream>>>(cntmat, rowtot);
        k_scanB<<<1, 256, 0, stream>>>(rowtot, bbase);

        k_reorder<<<GB, 256, 0, stream>>>(eidx, cntmat, bbase, sp, E_, T);

        e_stats1<<<2048, 256, 0, stream>>>(sp, h, mw1, mb1, sums, E_);

        e_pass2<<<2048, 256, 0, stream>>>(sp, h, mw1, mb1, sums, mg1, mbe1, invE,
                                          mw2, mb2, sums + 16, E_);

        e_aggr_part<<<nbuckets * SPLIT, 256, 0, stream>>>(sp, h, bbase, rowtot,
                                                          mw1, mb1, sums, mg1, mbe1,
                                                          sums + 16, mg2, mbe2, invE,
                                                          mw2, mb2, part);
        k_merge<<<nblk, 256, 0, stream>>>(part, acc, n);

        n_stats1<<<nblk, 256, 0, stream>>>(h, acc, uw1, ub1, sums + 24, n);
        n_stats2<<<nblk, 256, 0, stream>>>(h, acc, uw1, ub1, sums + 24, ug1, ube1, invN,
                                           uw2, ub2, sums + 40, n);
        n_final<<<nblk, 256, 0, stream>>>(h, acc, uw1, ub1, sums + 24, ug1, ube1,
                                          sums + 40, ug2, ube2, invN,
                                          uw2, ub2, pw, pb, (float2*)d_out, n);
    } else {
        (void)hipMemsetAsync(acc, 0, 32 * (size_t)n + 256, stream);

        fb_stats1<<<4096, 256, 0, stream>>>(eidx, h, mw1, mb1, sums, acc, E_);
        k_fin<<<1, 64, 0, stream>>>(sums, ss, mg1, mbe1, 8, invE);

        fb_stats2<<<4096, 256, 0, stream>>>(eidx, h, mw1, mb1, ss, mw2, mb2, sums + 16, E_);
        k_fin<<<1, 64, 0, stream>>>(sums + 16, ss + 16, mg2, mbe2, 4, invE);

        fb_scatter<<<4096, 256, 0, stream>>>(eidx, h, mw1, mb1, ss, mw2, mb2, ss + 16, acc, E_);

        n_stats1<<<nblk, 256, 0, stream>>>(h, acc, uw1, ub1, sums + 24, n);
        n_stats2<<<nblk, 256, 0, stream>>>(h, acc, uw1, ub1, sums + 24, ug1, ube1, invN,
                                           uw2, ub2, sums + 40, n);
        n_final<<<nblk, 256, 0, stream>>>(h, acc, uw1, ub1, sums + 24, ug1, ube1,
                                          sums + 40, ug2, ube2, invN,
                                          uw2, ub2, pw, pb, (float2*)d_out, n);
    }
}